// Round 3
// baseline (176.453 us; speedup 1.0000x reference)
//
#include <hip/hip_runtime.h>
#include <math.h>

#define BB 2
#define HH 256
#define WW 832
#define HWIMG (HH * WW)
#define BHW (BB * HWIMG)

#define TXN 26            // tiles in x (832/32)
#define TYN 8             // tiles in y (256/32)
#define NTILES (BB * TXN * TYN)   // 416
#define CAP 512           // per-tile candidate capacity
#define KCAP 16384        // keeper list capacity

// prep tile
#define PTX 64
#define PTY 4

// ---------------------------------------------------------------------------
// Pass 1 (fused): 3x3 wrap box-blur + gradient/atan2 orientation for src&dst,
// plus src keeper compaction (5x5 min-linear-index test).
// ---------------------------------------------------------------------------
__global__ void prep_kernel(const float* __restrict__ src, const float* __restrict__ dst,
                            float* __restrict__ thS, float* __restrict__ thD,
                            int* __restrict__ kcount, int* __restrict__ klist) {
    __shared__ float lsS[(PTY + 4) * (PTX + 4)];   // staged src, halo 2, wrap-indexed
    __shared__ float lsD[(PTY + 4) * (PTX + 4)];
    __shared__ float blS[(PTY + 2) * (PTX + 2)];   // 3x3 box sums, halo 1
    __shared__ float blD[(PTY + 2) * (PTX + 2)];

    const int LW = PTX + 4;   // 68
    const int BW = PTX + 2;   // 66
    int tid = threadIdx.y * PTX + threadIdx.x;
    int ti = blockIdx.y * PTY;      // tile origin row
    int tj = blockIdx.x * PTX;      // tile origin col
    int b = blockIdx.z;
    const float* s = src + b * HWIMG;
    const float* d = dst + b * HWIMG;

    for (int t = tid; t < (PTY + 4) * LW; t += PTX * PTY) {
        int ly = t / LW, lx = t % LW;
        int gi = ti + ly - 2;
        int gj = tj + lx - 2;
        gi = (gi + HH) % HH;          // wrap (jnp.roll semantics for blur)
        gj = (gj + WW) % WW;
        lsS[t] = s[gi * WW + gj];
        lsD[t] = d[gi * WW + gj];
    }
    __syncthreads();

    for (int t = tid; t < (PTY + 2) * BW; t += PTX * PTY) {
        int ly = t / BW, lx = t % BW;        // center at staged (ly+1, lx+1)
        float aS = 0.f, aD = 0.f;
#pragma unroll
        for (int di = 0; di <= 2; ++di)
#pragma unroll
            for (int dj = 0; dj <= 2; ++dj) {
                int o = (ly + di) * LW + lx + dj;
                aS += lsS[o];
                aD += lsD[o];
            }
        blS[t] = aS;
        blD[t] = aD;
    }
    __syncthreads();

    int i = ti + threadIdx.y;
    int j = tj + threadIdx.x;
    int bc = (threadIdx.y + 1) * BW + threadIdx.x + 1;   // my blur index
    int idx = b * HWIMG + i * WW + j;

    // gradient (one-sided at image borders) + atan2, both maps
    {
        float gyg, gxg;
        if (i == 0)            gyg = blS[bc + BW] - blS[bc];
        else if (i == HH - 1)  gyg = blS[bc] - blS[bc - BW];
        else                   gyg = 0.5f * (blS[bc + BW] - blS[bc - BW]);
        if (j == 0)            gxg = blS[bc + 1] - blS[bc];
        else if (j == WW - 1)  gxg = blS[bc] - blS[bc - 1];
        else                   gxg = 0.5f * (blS[bc + 1] - blS[bc - 1]);
        thS[idx] = atan2f(gyg, gxg);

        if (i == 0)            gyg = blD[bc + BW] - blD[bc];
        else if (i == HH - 1)  gyg = blD[bc] - blD[bc - BW];
        else                   gyg = 0.5f * (blD[bc + BW] - blD[bc - BW]);
        if (j == 0)            gxg = blD[bc + 1] - blD[bc];
        else if (j == WW - 1)  gxg = blD[bc] - blD[bc - 1];
        else                   gxg = 0.5f * (blD[bc + 1] - blD[bc - 1]);
        thD[idx] = atan2f(gyg, gxg);
    }

    // keeper test: edge pixel with no smaller-linear-index edge in 5x5 window.
    // nl < mylin  <=>  di < 0, or di == 0 && dj < 0.
    int sc = (threadIdx.y + 2) * LW + threadIdx.x + 2;   // my staged index
    if (lsS[sc] > 0.5f) {
        bool keep = true;
        for (int di = -2; di < 0 && keep; ++di) {
            if (i + di < 0) continue;                    // OOB rows excluded (no wrap here)
            for (int dj = -2; dj <= 2; ++dj) {
                int jj = j + dj;
                if (jj < 0 || jj >= WW) continue;
                if (lsS[sc + di * LW + dj] > 0.5f) { keep = false; break; }
            }
        }
        if (keep) {
            for (int dj = -2; dj < 0; ++dj) {
                int jj = j + dj;
                if (jj < 0) continue;
                if (lsS[sc + dj] > 0.5f) { keep = false; break; }
            }
        }
        if (keep) {
            int pos = atomicAdd(kcount, 1);
            if (pos < KCAP) klist[pos] = j | (i << 10) | (b << 18);
        }
    }
}

// ---------------------------------------------------------------------------
// Pass 2: wave-per-keeper correspondence search + tile binning.
// 64 lanes cover the K=105 offsets (<=2 each); shuffle argmin with
// lexicographic (score, k) tie-break == jnp.argmin first-occurrence.
// ---------------------------------------------------------------------------
__global__ void search_kernel(const float* __restrict__ dst, const float* __restrict__ thD,
                              const float* __restrict__ thS,
                              const int* __restrict__ xx, const int* __restrict__ yy, int K,
                              const int* __restrict__ kcount, const int* __restrict__ klist,
                              int* __restrict__ counts, int* __restrict__ entries) {
    __shared__ int kox[128], koy[128];
    __shared__ float kd[128];
    for (int t = threadIdx.x; t < K; t += blockDim.x) {
        int ox = xx[t], oy = yy[t];
        kox[t] = ox; koy[t] = oy;
        kd[t] = 20.0f * sqrtf((float)(ox * ox + oy * oy));
    }
    __syncthreads();

    int lane = threadIdx.x & 63;
    int wave = (blockIdx.x * blockDim.x + threadIdx.x) >> 6;
    int nwaves = (gridDim.x * blockDim.x) >> 6;
    int nk = *kcount;
    if (nk > KCAP) nk = KCAP;

    for (int w = wave; w < nk; w += nwaves) {
        int rec = klist[w];
        int j = rec & 1023;
        int i = (rec >> 10) & 255;
        int b = rec >> 18;
        const float* d = dst + b * HWIMG;
        const float* td = thD + b * HWIMG;
        float ts = thS[b * HWIMG + i * WW + j];

        float best = 1e9f;
        int bk = 1 << 20;
#pragma unroll
        for (int r = 0; r < 2; ++r) {
            int k = lane + r * 64;
            if (k < K) {
                int ii = i + koy[k], jj = j + kox[k];
                if (ii >= 0 && ii < HH && jj >= 0 && jj < WW && d[ii * WW + jj] > 0.5f) {
                    float sc = kd[k] + 10.5f * (1.0f - cosf(ts - td[ii * WW + jj]));
                    if (sc < best || (sc == best && k < bk)) { best = sc; bk = k; }
                }
            }
        }
#pragma unroll
        for (int off = 32; off >= 1; off >>= 1) {
            float ob = __shfl_down(best, off, 64);
            int ok = __shfl_down(bk, off, 64);
            if (ob < best || (ob == best && ok < bk)) { best = ob; bk = ok; }
        }
        if (lane == 0 && best < 5e8f) {
            int dx = kox[bk], dy = koy[bk];
            int packed = j | (i << 10) | ((dx + 7) << 18) | ((dy + 3) << 22);
            int tx0 = max(j - 10, 0) >> 5, tx1 = min(j + 10, WW - 1) >> 5;
            int ty0 = max(i - 10, 0) >> 5, ty1 = min(i + 10, HH - 1) >> 5;
            for (int ty = ty0; ty <= ty1; ++ty)
                for (int tx = tx0; tx <= tx1; ++tx) {
                    int tile = (b * TYN + ty) * TXN + tx;
                    int pos = atomicAdd(&counts[tile], 1);
                    if (pos < CAP) entries[tile * CAP + pos] = packed;
                }
        }
    }
}

// ---------------------------------------------------------------------------
// Pass 3: per-tile sparse diffusion (unchanged structure).
// ---------------------------------------------------------------------------
__global__ void diffuse_kernel(const int* __restrict__ counts, const int* __restrict__ entries,
                               float* __restrict__ out) {
    __shared__ float wt[441];
    __shared__ float4 ent[CAP];
    int tid = threadIdx.y * 32 + threadIdx.x;
    for (int t = tid; t < 441; t += 256) {
        int dy = t / 21 - 10;
        int dx = t % 21 - 10;
        wt[t] = expf(-sqrtf((float)(dx * dx + dy * dy)) / 5.0f);
    }
    int tx = blockIdx.x, ty = blockIdx.y, b = blockIdx.z;
    int tile = (b * TYN + ty) * TXN + tx;
    int cnt = counts[tile];
    if (cnt > CAP) cnt = CAP;
    const int* e = entries + tile * CAP;
    for (int t = tid; t < cnt; t += 256) {
        int p = e[t];
        ent[t] = make_float4((float)(p & 1023), (float)((p >> 10) & 255),
                             (float)(((p >> 18) & 15) - 7), (float)(((p >> 22) & 7) - 3));
    }
    __syncthreads();

    int j = tx * 32 + threadIdx.x;
    int i0 = ty * 32 + threadIdx.y * 4;
    float nx0 = 0, ny0 = 0, de0 = 0;
    float nx1 = 0, ny1 = 0, de1 = 0;
    float nx2 = 0, ny2 = 0, de2 = 0;
    float nx3 = 0, ny3 = 0, de3 = 0;

    for (int c = 0; c < cnt; ++c) {
        float4 E = ent[c];
        int dj = (int)E.x - j;
        if (dj < -10 || dj > 10) continue;
        int di = (int)E.y - i0;
        const float* wrow = &wt[dj + 10];
        if (di >= -10 && di <= 10) { float w = wrow[(di + 10) * 21]; de0 += w; nx0 += w * E.z; ny0 += w * E.w; }
        if (di >= -9  && di <= 11) { float w = wrow[(di + 9)  * 21]; de1 += w; nx1 += w * E.z; ny1 += w * E.w; }
        if (di >= -8  && di <= 12) { float w = wrow[(di + 8)  * 21]; de2 += w; nx2 += w * E.z; ny2 += w * E.w; }
        if (di >= -7  && di <= 13) { float w = wrow[(di + 7)  * 21]; de3 += w; nx3 += w * E.z; ny3 += w * E.w; }
    }

    int obase = b * 2 * HWIMG;
    float inv;
    inv = 0.6f / (de0 + 1e-6f);
    out[obase + (i0 + 0) * WW + j] = (float)j + nx0 * inv;
    out[obase + HWIMG + (i0 + 0) * WW + j] = (float)(i0 + 0) + ny0 * inv;
    inv = 0.6f / (de1 + 1e-6f);
    out[obase + (i0 + 1) * WW + j] = (float)j + nx1 * inv;
    out[obase + HWIMG + (i0 + 1) * WW + j] = (float)(i0 + 1) + ny1 * inv;
    inv = 0.6f / (de2 + 1e-6f);
    out[obase + (i0 + 2) * WW + j] = (float)j + nx2 * inv;
    out[obase + HWIMG + (i0 + 2) * WW + j] = (float)(i0 + 2) + ny2 * inv;
    inv = 0.6f / (de3 + 1e-6f);
    out[obase + (i0 + 3) * WW + j] = (float)j + nx3 * inv;
    out[obase + HWIMG + (i0 + 3) * WW + j] = (float)(i0 + 3) + ny3 * inv;
}

// ---------------------------------------------------------------------------
extern "C" void kernel_launch(void* const* d_in, const int* in_sizes, int n_in,
                              void* d_out, int out_size, void* d_ws, size_t ws_size,
                              hipStream_t stream) {
    const float* src = (const float*)d_in[0];
    const float* dst = (const float*)d_in[1];
    const int* xx = (const int*)d_in[2];
    const int* yy = (const int*)d_in[3];
    int K = in_sizes[2];  // 105

    float* ws = (float*)d_ws;
    float* thS = ws;
    float* thD = ws + (size_t)BHW;
    int* counts  = (int*)(ws + 2 * (size_t)BHW);   // [NTILES]
    int* kcount  = counts + NTILES;                // [1]  (contiguous -> one memset)
    int* klist   = kcount + 1;                     // [KCAP]
    int* entries = klist + KCAP;                   // [NTILES*CAP]
    float* out = (float*)d_out;

    hipMemsetAsync(counts, 0, (NTILES + 1) * sizeof(int), stream);
    prep_kernel<<<dim3(WW / PTX, HH / PTY, BB), dim3(PTX, PTY), 0, stream>>>(
        src, dst, thS, thD, kcount, klist);
    search_kernel<<<dim3(256), dim3(256), 0, stream>>>(
        dst, thD, thS, xx, yy, K, kcount, klist, counts, entries);
    diffuse_kernel<<<dim3(TXN, TYN, BB), dim3(32, 8), 0, stream>>>(counts, entries, out);
}

// Round 4
// 170.906 us; speedup vs baseline: 1.0325x; 1.0325x over previous
//
#include <hip/hip_runtime.h>
#include <math.h>

#define BB 2
#define HH 256
#define WW 832
#define HWIMG (HH * WW)
#define BHW (BB * HWIMG)

#define TXN 26            // tiles in x (832/32)
#define TYN 8             // tiles in y (256/32)
#define NTILES (BB * TXN * TYN)   // 416
#define CAP 512           // per-tile candidate capacity
#define KCAP 16384        // keeper list capacity

// ---------------------------------------------------------------------------
// Orientation at (i,j): 3x3 wrap box-blur (jnp.roll) -> jnp.gradient
// (one-sided at array borders) -> atan2. Box sums of 0/1 are exact in fp32,
// so per-point recomputation is bit-identical to the dense pass.
// ---------------------------------------------------------------------------
__device__ inline float theta_at(const float* __restrict__ m, int i, int j) {
    int ri[5], cj[5];
#pragma unroll
    for (int t = 0; t < 5; ++t) {
        int r = i + t - 2; r = (r < 0) ? r + HH : (r >= HH ? r - HH : r);
        int c = j + t - 2; c = (c < 0) ? c + WW : (c >= WW ? c - WW : c);
        ri[t] = r * WW; cj[t] = c;
    }
    float S[5][5];
#pragma unroll
    for (int a = 0; a < 5; ++a)
#pragma unroll
        for (int c = 0; c < 5; ++c)
            S[a][c] = m[ri[a] + cj[c]];
    float ct[5], cm[5], cb[5];
#pragma unroll
    for (int c = 0; c < 5; ++c) {
        ct[c] = S[0][c] + S[1][c] + S[2][c];   // blur row i-1 colsum
        cm[c] = S[1][c] + S[2][c] + S[3][c];   // blur row i   colsum
        cb[c] = S[2][c] + S[3][c] + S[4][c];   // blur row i+1 colsum
    }
    float Bm = ct[1] + ct[2] + ct[3];   // blur(i-1,j)
    float Bp = cb[1] + cb[2] + cb[3];   // blur(i+1,j)
    float Bl = cm[0] + cm[1] + cm[2];   // blur(i,j-1)
    float Br = cm[2] + cm[3] + cm[4];   // blur(i,j+1)
    float Bc = cm[1] + cm[2] + cm[3];   // blur(i,j)
    float gy = (i == 0) ? (Bp - Bc) : (i == HH - 1) ? (Bc - Bm) : 0.5f * (Bp - Bm);
    float gx = (j == 0) ? (Br - Bc) : (j == WW - 1) ? (Bc - Bl) : 0.5f * (Br - Bl);
    return atan2f(gy, gx);
}

// ---------------------------------------------------------------------------
// Pass 1: barrier-free sparse prep. Fast path = 2 coalesced loads/pixel.
// dst-edge pixels (~2%): compute+write thD. src-edge pixels: 5x5 keeper test
// (early-out); keepers compute thS and append (pos, packed, ts) to klist/kts.
// thD is only ever read at dst-edge probes, so non-edge entries stay poisoned.
// ---------------------------------------------------------------------------
__global__ void prep_kernel(const float* __restrict__ src, const float* __restrict__ dst,
                            float* __restrict__ thD,
                            int* __restrict__ kcount, int* __restrict__ klist,
                            float* __restrict__ kts) {
    int idx = blockIdx.x * blockDim.x + threadIdx.x;
    if (idx >= BHW) return;
    int j = idx % WW;
    int t = idx / WW;
    int i = t % HH;
    int b = t / HH;
    const float* s = src + b * HWIMG;
    const float* d = dst + b * HWIMG;
    int pij = i * WW + j;

    float dc = d[pij];
    float sc = s[pij];

    if (dc > 0.5f) thD[b * HWIMG + pij] = theta_at(d, i, j);

    if (sc > 0.5f) {
        // keep iff no edge with smaller linear index in 5x5 window:
        // di<0 (any dj), or di==0 && dj<0. OOB excluded (no wrap here).
        bool keep = true;
        for (int di = -2; di < 0 && keep; ++di) {
            int ii = i + di;
            if (ii < 0) continue;
            int rb = ii * WW;
            for (int dj = -2; dj <= 2; ++dj) {
                int jj = j + dj;
                if (jj < 0 || jj >= WW) continue;
                if (s[rb + jj] > 0.5f) { keep = false; break; }
            }
        }
        if (keep) {
            for (int dj = -2; dj < 0; ++dj) {
                if (j + dj < 0) continue;
                if (s[pij + dj] > 0.5f) { keep = false; break; }
            }
        }
        if (keep) {
            float ts = theta_at(s, i, j);
            int pos = atomicAdd(kcount, 1);
            if (pos < KCAP) {
                klist[pos] = j | (i << 10) | (b << 18);
                kts[pos] = ts;
            }
        }
    }
}

// ---------------------------------------------------------------------------
// Pass 2: wave-per-keeper correspondence search + tile binning.
// 64 lanes cover K=105 offsets (<=2 each); shuffle argmin with lexicographic
// (score, k) tie-break == jnp.argmin first-occurrence.
// ---------------------------------------------------------------------------
__global__ void search_kernel(const float* __restrict__ dst, const float* __restrict__ thD,
                              const int* __restrict__ xx, const int* __restrict__ yy, int K,
                              const int* __restrict__ kcount, const int* __restrict__ klist,
                              const float* __restrict__ kts,
                              int* __restrict__ counts, int* __restrict__ entries) {
    __shared__ int kox[128], koy[128];
    __shared__ float kd[128];
    for (int t = threadIdx.x; t < K; t += blockDim.x) {
        int ox = xx[t], oy = yy[t];
        kox[t] = ox; koy[t] = oy;
        kd[t] = 20.0f * sqrtf((float)(ox * ox + oy * oy));
    }
    __syncthreads();

    int lane = threadIdx.x & 63;
    int wave = (blockIdx.x * blockDim.x + threadIdx.x) >> 6;
    int nwaves = (gridDim.x * blockDim.x) >> 6;
    int nk = *kcount;
    if (nk > KCAP) nk = KCAP;

    for (int w = wave; w < nk; w += nwaves) {
        int rec = klist[w];
        int j = rec & 1023;
        int i = (rec >> 10) & 255;
        int b = rec >> 18;
        const float* d = dst + b * HWIMG;
        const float* td = thD + b * HWIMG;
        float ts = kts[w];

        float best = 1e9f;
        int bk = 1 << 20;
#pragma unroll
        for (int r = 0; r < 2; ++r) {
            int k = lane + r * 64;
            if (k < K) {
                int ii = i + koy[k], jj = j + kox[k];
                if (ii >= 0 && ii < HH && jj >= 0 && jj < WW && d[ii * WW + jj] > 0.5f) {
                    float sc = kd[k] + 10.5f * (1.0f - cosf(ts - td[ii * WW + jj]));
                    if (sc < best || (sc == best && k < bk)) { best = sc; bk = k; }
                }
            }
        }
#pragma unroll
        for (int off = 32; off >= 1; off >>= 1) {
            float ob = __shfl_down(best, off, 64);
            int ok = __shfl_down(bk, off, 64);
            if (ob < best || (ob == best && ok < bk)) { best = ob; bk = ok; }
        }
        if (lane == 0 && best < 5e8f) {
            int dx = kox[bk], dy = koy[bk];
            int packed = j | (i << 10) | ((dx + 7) << 18) | ((dy + 3) << 22);
            int tx0 = max(j - 10, 0) >> 5, tx1 = min(j + 10, WW - 1) >> 5;
            int ty0 = max(i - 10, 0) >> 5, ty1 = min(i + 10, HH - 1) >> 5;
            for (int ty = ty0; ty <= ty1; ++ty)
                for (int tx = tx0; tx <= tx1; ++tx) {
                    int tile = (b * TYN + ty) * TXN + tx;
                    int pos = atomicAdd(&counts[tile], 1);
                    if (pos < CAP) entries[tile * CAP + pos] = packed;
                }
        }
    }
}

// ---------------------------------------------------------------------------
// Pass 3: per-tile sparse diffusion.
// ---------------------------------------------------------------------------
__global__ void diffuse_kernel(const int* __restrict__ counts, const int* __restrict__ entries,
                               float* __restrict__ out) {
    __shared__ float wt[441];
    __shared__ float4 ent[CAP];
    int tid = threadIdx.y * 32 + threadIdx.x;
    for (int t = tid; t < 441; t += 256) {
        int dy = t / 21 - 10;
        int dx = t % 21 - 10;
        wt[t] = expf(-sqrtf((float)(dx * dx + dy * dy)) / 5.0f);
    }
    int tx = blockIdx.x, ty = blockIdx.y, b = blockIdx.z;
    int tile = (b * TYN + ty) * TXN + tx;
    int cnt = counts[tile];
    if (cnt > CAP) cnt = CAP;
    const int* e = entries + tile * CAP;
    for (int t = tid; t < cnt; t += 256) {
        int p = e[t];
        ent[t] = make_float4((float)(p & 1023), (float)((p >> 10) & 255),
                             (float)(((p >> 18) & 15) - 7), (float)(((p >> 22) & 7) - 3));
    }
    __syncthreads();

    int j = tx * 32 + threadIdx.x;
    int i0 = ty * 32 + threadIdx.y * 4;
    float nx0 = 0, ny0 = 0, de0 = 0;
    float nx1 = 0, ny1 = 0, de1 = 0;
    float nx2 = 0, ny2 = 0, de2 = 0;
    float nx3 = 0, ny3 = 0, de3 = 0;

    for (int c = 0; c < cnt; ++c) {
        float4 E = ent[c];
        int dj = (int)E.x - j;
        if (dj < -10 || dj > 10) continue;
        int di = (int)E.y - i0;
        const float* wrow = &wt[dj + 10];
        if (di >= -10 && di <= 10) { float w = wrow[(di + 10) * 21]; de0 += w; nx0 += w * E.z; ny0 += w * E.w; }
        if (di >= -9  && di <= 11) { float w = wrow[(di + 9)  * 21]; de1 += w; nx1 += w * E.z; ny1 += w * E.w; }
        if (di >= -8  && di <= 12) { float w = wrow[(di + 8)  * 21]; de2 += w; nx2 += w * E.z; ny2 += w * E.w; }
        if (di >= -7  && di <= 13) { float w = wrow[(di + 7)  * 21]; de3 += w; nx3 += w * E.z; ny3 += w * E.w; }
    }

    int obase = b * 2 * HWIMG;
    float inv;
    inv = 0.6f / (de0 + 1e-6f);
    out[obase + (i0 + 0) * WW + j] = (float)j + nx0 * inv;
    out[obase + HWIMG + (i0 + 0) * WW + j] = (float)(i0 + 0) + ny0 * inv;
    inv = 0.6f / (de1 + 1e-6f);
    out[obase + (i0 + 1) * WW + j] = (float)j + nx1 * inv;
    out[obase + HWIMG + (i0 + 1) * WW + j] = (float)(i0 + 1) + ny1 * inv;
    inv = 0.6f / (de2 + 1e-6f);
    out[obase + (i0 + 2) * WW + j] = (float)j + nx2 * inv;
    out[obase + HWIMG + (i0 + 2) * WW + j] = (float)(i0 + 2) + ny2 * inv;
    inv = 0.6f / (de3 + 1e-6f);
    out[obase + (i0 + 3) * WW + j] = (float)j + nx3 * inv;
    out[obase + HWIMG + (i0 + 3) * WW + j] = (float)(i0 + 3) + ny3 * inv;
}

// ---------------------------------------------------------------------------
extern "C" void kernel_launch(void* const* d_in, const int* in_sizes, int n_in,
                              void* d_out, int out_size, void* d_ws, size_t ws_size,
                              hipStream_t stream) {
    const float* src = (const float*)d_in[0];
    const float* dst = (const float*)d_in[1];
    const int* xx = (const int*)d_in[2];
    const int* yy = (const int*)d_in[3];
    int K = in_sizes[2];  // 105

    float* ws = (float*)d_ws;
    float* thD = ws;                               // [BHW]
    int* counts  = (int*)(ws + (size_t)BHW);       // [NTILES]
    int* kcount  = counts + NTILES;                // [1]
    int* klist   = kcount + 1;                     // [KCAP]
    float* kts   = (float*)(klist + KCAP);         // [KCAP]
    int* entries = (int*)(kts + KCAP);             // [NTILES*CAP]
    float* out = (float*)d_out;

    hipMemsetAsync(counts, 0, (NTILES + 1) * sizeof(int), stream);
    prep_kernel<<<dim3((BHW + 255) / 256), dim3(256), 0, stream>>>(
        src, dst, thD, kcount, klist, kts);
    search_kernel<<<dim3(256), dim3(256), 0, stream>>>(
        dst, thD, xx, yy, K, kcount, klist, kts, counts, entries);
    diffuse_kernel<<<dim3(TXN, TYN, BB), dim3(32, 8), 0, stream>>>(counts, entries, out);
}

// Round 5
// 152.412 us; speedup vs baseline: 1.1577x; 1.1213x over previous
//
#include <hip/hip_runtime.h>
#include <math.h>

#define BB 2
#define HH 256
#define WW 832
#define HWIMG (HH * WW)
#define BHW (BB * HWIMG)

#define TXN 26            // tiles in x (832/32)
#define TYN 8             // tiles in y (256/32)
#define NTILES (BB * TXN * TYN)   // 416
#define CAP 512           // per-tile candidate capacity
#define KCAP 16384        // keeper list capacity
#define ECAP 32768        // edge list capacity (expected ~8.5K each)

// ---------------------------------------------------------------------------
// Orientation at (i,j): 3x3 wrap box-blur (jnp.roll) -> jnp.gradient
// (one-sided at borders) -> atan2. Box sums of 0/1 are exact in fp32, so
// per-point recomputation is bit-identical to the dense pass. All 25 loads
// independent -> single memory round trip.
// ---------------------------------------------------------------------------
__device__ inline float theta_at(const float* __restrict__ m, int i, int j) {
    int ri[5], cj[5];
#pragma unroll
    for (int t = 0; t < 5; ++t) {
        int r = i + t - 2; r = (r < 0) ? r + HH : (r >= HH ? r - HH : r);
        int c = j + t - 2; c = (c < 0) ? c + WW : (c >= WW ? c - WW : c);
        ri[t] = r * WW; cj[t] = c;
    }
    float S[5][5];
#pragma unroll
    for (int a = 0; a < 5; ++a)
#pragma unroll
        for (int c = 0; c < 5; ++c)
            S[a][c] = m[ri[a] + cj[c]];
    float ct[5], cm[5], cb[5];
#pragma unroll
    for (int c = 0; c < 5; ++c) {
        ct[c] = S[0][c] + S[1][c] + S[2][c];
        cm[c] = S[1][c] + S[2][c] + S[3][c];
        cb[c] = S[2][c] + S[3][c] + S[4][c];
    }
    float Bm = ct[1] + ct[2] + ct[3];
    float Bp = cb[1] + cb[2] + cb[3];
    float Bl = cm[0] + cm[1] + cm[2];
    float Br = cm[2] + cm[3] + cm[4];
    float Bc = cm[1] + cm[2] + cm[3];
    float gy = (i == 0) ? (Bp - Bc) : (i == HH - 1) ? (Bc - Bm) : 0.5f * (Bp - Bm);
    float gx = (j == 0) ? (Br - Bc) : (j == WW - 1) ? (Bc - Bl) : 0.5f * (Br - Bl);
    return atan2f(gy, gx);
}

// Wave-aggregated list append: shfl prefix-sum, one atomic per wave.
// All 64 lanes must be active (grids are exact multiples of 64).
__device__ inline int wave_append(int* counter, int myc, int lane) {
    int off = myc;
#pragma unroll
    for (int d = 1; d < 64; d <<= 1) {
        int n = __shfl_up(off, d, 64);
        if (lane >= d) off += n;
    }
    int tot = __shfl(off, 63, 64);
    int base = 0;
    if (lane == 63 && tot > 0) base = atomicAdd(counter, tot);
    base = __shfl(base, 63, 64);
    return base + off - myc;   // exclusive offset for this lane
}

// ---------------------------------------------------------------------------
// Pass 1: dense classify-and-compact. float4 loads, no divergence, no
// dependent loads. rec = j | i<<10 | b<<18.
// ---------------------------------------------------------------------------
__global__ void scan_kernel(const float4* __restrict__ src4, const float4* __restrict__ dst4,
                            int* __restrict__ scount, int* __restrict__ slist,
                            int* __restrict__ dcount, int* __restrict__ dlist) {
    int t = blockIdx.x * blockDim.x + threadIdx.x;   // exact: BHW/4 threads
    float4 sv = src4[t];
    float4 dv = dst4[t];
    int p0 = t * 4;
    int j = p0 % WW;          // multiple of 4; j+3 <= 831 stays in 10-bit field
    int r = p0 / WW;
    int rec0 = j | ((r % HH) << 10) | ((r / HH) << 18);
    int sm = (sv.x > 0.5f ? 1 : 0) | (sv.y > 0.5f ? 2 : 0) | (sv.z > 0.5f ? 4 : 0) | (sv.w > 0.5f ? 8 : 0);
    int dm = (dv.x > 0.5f ? 1 : 0) | (dv.y > 0.5f ? 2 : 0) | (dv.z > 0.5f ? 4 : 0) | (dv.w > 0.5f ? 8 : 0);
    int lane = threadIdx.x & 63;

    int o = wave_append(scount, __popc(sm), lane);
#pragma unroll
    for (int q = 0; q < 4; ++q)
        if (sm & (1 << q)) { if (o < ECAP) slist[o] = rec0 + q; ++o; }
    o = wave_append(dcount, __popc(dm), lane);
#pragma unroll
    for (int q = 0; q < 4; ++q)
        if (dm & (1 << q)) { if (o < ECAP) dlist[o] = rec0 + q; ++o; }
}

// ---------------------------------------------------------------------------
// Pass 2: grid-stride over compact lists (all lanes active).
//   t <  nd : dst edge -> thD[pixel] = theta_at(dst)
//   t >= nd : src edge -> keeper test (12 INDEPENDENT clamped loads, no
//             early-out) ; keepers append (rec, thS) to klist/kts.
// ---------------------------------------------------------------------------
__global__ void edge_theta_kernel(const float* __restrict__ src, const float* __restrict__ dst,
                                  const int* __restrict__ scount, const int* __restrict__ slist,
                                  const int* __restrict__ dcount, const int* __restrict__ dlist,
                                  float* __restrict__ thD,
                                  int* __restrict__ kcount, int* __restrict__ klist,
                                  float* __restrict__ kts) {
    int nd = *dcount; if (nd > ECAP) nd = ECAP;
    int ns = *scount; if (ns > ECAP) ns = ECAP;
    int tot = nd + ns;
    for (int t = blockIdx.x * blockDim.x + threadIdx.x; t < tot; t += gridDim.x * blockDim.x) {
        if (t < nd) {
            int rec = dlist[t];
            int j = rec & 1023, i = (rec >> 10) & 255, b = rec >> 18;
            thD[b * HWIMG + i * WW + j] = theta_at(dst + b * HWIMG, i, j);
        } else {
            int rec = slist[t - nd];
            int j = rec & 1023, i = (rec >> 10) & 255, b = rec >> 18;
            const float* s = src + b * HWIMG;
            // neighbors with smaller linear index: rows i-2,i-1 (dj -2..2), row i (dj -2,-1)
            float m = 0.f;
#pragma unroll
            for (int p = 0; p < 12; ++p) {
                int di = (p < 5) ? -2 : (p < 10 ? -1 : 0);
                int dj = (p < 5) ? (p - 2) : (p < 10 ? (p - 7) : (p - 12));
                int ii = i + di, jj = j + dj;
                bool inb = (ii >= 0) && (jj >= 0) && (jj < WW);
                float v = s[inb ? (ii * WW + jj) : 0];
                m = fmaxf(m, inb ? v : 0.f);
            }
            if (m <= 0.5f) {
                float ts = theta_at(s, i, j);
                int pos = atomicAdd(kcount, 1);
                if (pos < KCAP) { klist[pos] = rec; kts[pos] = ts; }
            }
        }
    }
}

// ---------------------------------------------------------------------------
// Pass 3: wave-per-keeper search + tile binning. Lexicographic (score,k)
// shuffle argmin == jnp.argmin first-occurrence.
// ---------------------------------------------------------------------------
__global__ void search_kernel(const float* __restrict__ dst, const float* __restrict__ thD,
                              const int* __restrict__ xx, const int* __restrict__ yy, int K,
                              const int* __restrict__ kcount, const int* __restrict__ klist,
                              const float* __restrict__ kts,
                              int* __restrict__ counts, int* __restrict__ entries) {
    __shared__ int kox[128], koy[128];
    __shared__ float kd[128];
    for (int t = threadIdx.x; t < K; t += blockDim.x) {
        int ox = xx[t], oy = yy[t];
        kox[t] = ox; koy[t] = oy;
        kd[t] = 20.0f * sqrtf((float)(ox * ox + oy * oy));
    }
    __syncthreads();

    int lane = threadIdx.x & 63;
    int wave = (blockIdx.x * blockDim.x + threadIdx.x) >> 6;
    int nwaves = (gridDim.x * blockDim.x) >> 6;
    int nk = *kcount;
    if (nk > KCAP) nk = KCAP;

    for (int w = wave; w < nk; w += nwaves) {
        int rec = klist[w];
        int j = rec & 1023;
        int i = (rec >> 10) & 255;
        int b = rec >> 18;
        const float* d = dst + b * HWIMG;
        const float* td = thD + b * HWIMG;
        float ts = kts[w];

        float best = 1e9f;
        int bk = 1 << 20;
#pragma unroll
        for (int r = 0; r < 2; ++r) {
            int k = lane + r * 64;
            if (k < K) {
                int ii = i + koy[k], jj = j + kox[k];
                if (ii >= 0 && ii < HH && jj >= 0 && jj < WW && d[ii * WW + jj] > 0.5f) {
                    float sc = kd[k] + 10.5f * (1.0f - cosf(ts - td[ii * WW + jj]));
                    if (sc < best || (sc == best && k < bk)) { best = sc; bk = k; }
                }
            }
        }
#pragma unroll
        for (int off = 32; off >= 1; off >>= 1) {
            float ob = __shfl_down(best, off, 64);
            int ok = __shfl_down(bk, off, 64);
            if (ob < best || (ob == best && ok < bk)) { best = ob; bk = ok; }
        }
        if (lane == 0 && best < 5e8f) {
            int dx = kox[bk], dy = koy[bk];
            int packed = j | (i << 10) | ((dx + 7) << 18) | ((dy + 3) << 22);
            int tx0 = max(j - 10, 0) >> 5, tx1 = min(j + 10, WW - 1) >> 5;
            int ty0 = max(i - 10, 0) >> 5, ty1 = min(i + 10, HH - 1) >> 5;
            for (int ty = ty0; ty <= ty1; ++ty)
                for (int tx = tx0; tx <= tx1; ++tx) {
                    int tile = (b * TYN + ty) * TXN + tx;
                    int pos = atomicAdd(&counts[tile], 1);
                    if (pos < CAP) entries[tile * CAP + pos] = packed;
                }
        }
    }
}

// ---------------------------------------------------------------------------
// Pass 4: per-tile sparse diffusion.
// ---------------------------------------------------------------------------
__global__ void diffuse_kernel(const int* __restrict__ counts, const int* __restrict__ entries,
                               float* __restrict__ out) {
    __shared__ float wt[441];
    __shared__ float4 ent[CAP];
    int tid = threadIdx.y * 32 + threadIdx.x;
    for (int t = tid; t < 441; t += 256) {
        int dy = t / 21 - 10;
        int dx = t % 21 - 10;
        wt[t] = expf(-sqrtf((float)(dx * dx + dy * dy)) / 5.0f);
    }
    int tx = blockIdx.x, ty = blockIdx.y, b = blockIdx.z;
    int tile = (b * TYN + ty) * TXN + tx;
    int cnt = counts[tile];
    if (cnt > CAP) cnt = CAP;
    const int* e = entries + tile * CAP;
    for (int t = tid; t < cnt; t += 256) {
        int p = e[t];
        ent[t] = make_float4((float)(p & 1023), (float)((p >> 10) & 255),
                             (float)(((p >> 18) & 15) - 7), (float)(((p >> 22) & 7) - 3));
    }
    __syncthreads();

    int j = tx * 32 + threadIdx.x;
    int i0 = ty * 32 + threadIdx.y * 4;
    float nx0 = 0, ny0 = 0, de0 = 0;
    float nx1 = 0, ny1 = 0, de1 = 0;
    float nx2 = 0, ny2 = 0, de2 = 0;
    float nx3 = 0, ny3 = 0, de3 = 0;

    for (int c = 0; c < cnt; ++c) {
        float4 E = ent[c];
        int dj = (int)E.x - j;
        if (dj < -10 || dj > 10) continue;
        int di = (int)E.y - i0;
        const float* wrow = &wt[dj + 10];
        if (di >= -10 && di <= 10) { float w = wrow[(di + 10) * 21]; de0 += w; nx0 += w * E.z; ny0 += w * E.w; }
        if (di >= -9  && di <= 11) { float w = wrow[(di + 9)  * 21]; de1 += w; nx1 += w * E.z; ny1 += w * E.w; }
        if (di >= -8  && di <= 12) { float w = wrow[(di + 8)  * 21]; de2 += w; nx2 += w * E.z; ny2 += w * E.w; }
        if (di >= -7  && di <= 13) { float w = wrow[(di + 7)  * 21]; de3 += w; nx3 += w * E.z; ny3 += w * E.w; }
    }

    int obase = b * 2 * HWIMG;
    float inv;
    inv = 0.6f / (de0 + 1e-6f);
    out[obase + (i0 + 0) * WW + j] = (float)j + nx0 * inv;
    out[obase + HWIMG + (i0 + 0) * WW + j] = (float)(i0 + 0) + ny0 * inv;
    inv = 0.6f / (de1 + 1e-6f);
    out[obase + (i0 + 1) * WW + j] = (float)j + nx1 * inv;
    out[obase + HWIMG + (i0 + 1) * WW + j] = (float)(i0 + 1) + ny1 * inv;
    inv = 0.6f / (de2 + 1e-6f);
    out[obase + (i0 + 2) * WW + j] = (float)j + nx2 * inv;
    out[obase + HWIMG + (i0 + 2) * WW + j] = (float)(i0 + 2) + ny2 * inv;
    inv = 0.6f / (de3 + 1e-6f);
    out[obase + (i0 + 3) * WW + j] = (float)j + nx3 * inv;
    out[obase + HWIMG + (i0 + 3) * WW + j] = (float)(i0 + 3) + ny3 * inv;
}

// ---------------------------------------------------------------------------
extern "C" void kernel_launch(void* const* d_in, const int* in_sizes, int n_in,
                              void* d_out, int out_size, void* d_ws, size_t ws_size,
                              hipStream_t stream) {
    const float* src = (const float*)d_in[0];
    const float* dst = (const float*)d_in[1];
    const int* xx = (const int*)d_in[2];
    const int* yy = (const int*)d_in[3];
    int K = in_sizes[2];  // 105

    float* ws = (float*)d_ws;
    float* thD   = ws;                              // [BHW]
    int* counts  = (int*)(ws + (size_t)BHW);        // [NTILES]
    int* kcount  = counts + NTILES;                 // [1]
    int* scount  = kcount + 1;                      // [1]
    int* dcount  = scount + 1;                      // [1]
    int* klist   = dcount + 1;                      // [KCAP]
    float* kts   = (float*)(klist + KCAP);          // [KCAP]
    int* slist   = (int*)(kts + KCAP);              // [ECAP]
    int* dlist   = slist + ECAP;                    // [ECAP]
    int* entries = dlist + ECAP;                    // [NTILES*CAP]
    float* out = (float*)d_out;

    hipMemsetAsync(counts, 0, (NTILES + 3) * sizeof(int), stream);
    scan_kernel<<<dim3(BHW / 4 / 256), dim3(256), 0, stream>>>(
        (const float4*)src, (const float4*)dst, scount, slist, dcount, dlist);
    edge_theta_kernel<<<dim3(128), dim3(256), 0, stream>>>(
        src, dst, scount, slist, dcount, dlist, thD, kcount, klist, kts);
    search_kernel<<<dim3(512), dim3(256), 0, stream>>>(
        dst, thD, xx, yy, K, kcount, klist, kts, counts, entries);
    diffuse_kernel<<<dim3(TXN, TYN, BB), dim3(32, 8), 0, stream>>>(counts, entries, out);
}

// Round 6
// 120.971 us; speedup vs baseline: 1.4586x; 1.2599x over previous
//
#include <hip/hip_runtime.h>
#include <math.h>

#define BB 2
#define HH 256
#define WW 832
#define HWIMG (HH * WW)
#define BHW (BB * HWIMG)

#define TXN 26            // tiles in x (832/32)
#define TYN 8             // tiles in y (256/32)
#define NTILES (BB * TXN * TYN)   // 416 == prep grid size (convenient)
#define CAP 512           // per-tile candidate capacity
#define KPB 384           // keepers per prep-block segment (expected ~16)

// ---------------------------------------------------------------------------
// Orientation at (i,j): 3x3 wrap box-blur (jnp.roll) -> jnp.gradient
// (one-sided at borders) -> atan2. Box sums of 0/1 exact in fp32; all 25
// loads independent -> one memory round trip.
// ---------------------------------------------------------------------------
__device__ inline float theta_at(const float* __restrict__ m, int i, int j) {
    int ri[5], cj[5];
#pragma unroll
    for (int t = 0; t < 5; ++t) {
        int r = i + t - 2; r = (r < 0) ? r + HH : (r >= HH ? r - HH : r);
        int c = j + t - 2; c = (c < 0) ? c + WW : (c >= WW ? c - WW : c);
        ri[t] = r * WW; cj[t] = c;
    }
    float S[5][5];
#pragma unroll
    for (int a = 0; a < 5; ++a)
#pragma unroll
        for (int c = 0; c < 5; ++c)
            S[a][c] = m[ri[a] + cj[c]];
    float ct[5], cm[5], cb[5];
#pragma unroll
    for (int c = 0; c < 5; ++c) {
        ct[c] = S[0][c] + S[1][c] + S[2][c];
        cm[c] = S[1][c] + S[2][c] + S[3][c];
        cb[c] = S[2][c] + S[3][c] + S[4][c];
    }
    float Bm = ct[1] + ct[2] + ct[3];
    float Bp = cb[1] + cb[2] + cb[3];
    float Bl = cm[0] + cm[1] + cm[2];
    float Br = cm[2] + cm[3] + cm[4];
    float Bc = cm[1] + cm[2] + cm[3];
    float gy = (i == 0) ? (Bp - Bc) : (i == HH - 1) ? (Bc - Bm) : 0.5f * (Bp - Bm);
    float gx = (j == 0) ? (Br - Bc) : (j == WW - 1) ? (Bc - Bl) : 0.5f * (Br - Bl);
    return atan2f(gy, gx);
}

// ---------------------------------------------------------------------------
// Pass 1 (fused): classify 4 px/thread; dst-edges -> thD scatter; src-edges ->
// keeper test (12 independent probes, no early-out); keepers -> per-block
// segment via LDS atomic (no global atomics anywhere). Also zeroes counts[].
// 416 blocks x 256 threads; block never straddles batch b (1024 | HWIMG).
// ---------------------------------------------------------------------------
__global__ void prep_kernel(const float4* __restrict__ src4, const float4* __restrict__ dst4,
                            const float* __restrict__ src, const float* __restrict__ dst,
                            float* __restrict__ thD,
                            int* __restrict__ kcnt, int* __restrict__ klist,
                            float* __restrict__ kts, int* __restrict__ counts) {
    __shared__ int nkeep;
    if (threadIdx.x == 0) { nkeep = 0; counts[blockIdx.x] = 0; }
    __syncthreads();

    int t = blockIdx.x * 256 + threadIdx.x;
    float4 sv = src4[t];
    float4 dv = dst4[t];
    int p0 = t * 4;
    int j0 = p0 % WW;            // multiple of 4; row not straddled (4 | WW)
    int r = p0 / WW;
    int i = r % HH;
    int b = r / HH;
    const float* sb = src + b * HWIMG;
    const float* db = dst + b * HWIMG;
    float svv[4] = {sv.x, sv.y, sv.z, sv.w};
    float dvv[4] = {dv.x, dv.y, dv.z, dv.w};

#pragma unroll
    for (int q = 0; q < 4; ++q) {
        int j = j0 + q;
        if (dvv[q] > 0.5f)
            thD[b * HWIMG + i * WW + j] = theta_at(db, i, j);
        if (svv[q] > 0.5f) {
            // smaller-linear-index neighbors: rows i-2,i-1 (dj -2..2), row i (dj -2,-1)
            float m = 0.f;
#pragma unroll
            for (int p = 0; p < 12; ++p) {
                int di = (p < 5) ? -2 : (p < 10 ? -1 : 0);
                int dj = (p < 5) ? (p - 2) : (p < 10 ? (p - 7) : (p - 12));
                int ii = i + di, jj = j + dj;
                bool inb = (ii >= 0) && (jj >= 0) && (jj < WW);
                float v = sb[inb ? (ii * WW + jj) : 0];
                m = fmaxf(m, inb ? v : 0.f);
            }
            if (m <= 0.5f) {
                float ts = theta_at(sb, i, j);
                int pos = atomicAdd(&nkeep, 1);          // LDS atomic, on-CU
                if (pos < KPB) {
                    klist[blockIdx.x * KPB + pos] = j | (i << 10) | (b << 18);
                    kts[blockIdx.x * KPB + pos] = ts;
                }
            }
        }
    }
    __syncthreads();
    if (threadIdx.x == 0) kcnt[blockIdx.x] = (nkeep < KPB) ? nkeep : KPB;
}

// ---------------------------------------------------------------------------
// Pass 2: segmented wave-per-keeper search + tile binning. Block b consumes
// segment b. Lexicographic (score,k) shuffle argmin == jnp.argmin.
// ---------------------------------------------------------------------------
__global__ void search_kernel(const float* __restrict__ dst, const float* __restrict__ thD,
                              const int* __restrict__ xx, const int* __restrict__ yy, int K,
                              const int* __restrict__ kcnt, const int* __restrict__ klist,
                              const float* __restrict__ kts,
                              int* __restrict__ counts, int* __restrict__ entries) {
    __shared__ int kox[128], koy[128];
    __shared__ float kd[128];
    for (int t = threadIdx.x; t < K; t += blockDim.x) {
        int ox = xx[t], oy = yy[t];
        kox[t] = ox; koy[t] = oy;
        kd[t] = 20.0f * sqrtf((float)(ox * ox + oy * oy));
    }
    __syncthreads();

    int lane = threadIdx.x & 63;
    int wv = threadIdx.x >> 6;          // 0..3
    int seg = blockIdx.x;
    int nk = kcnt[seg];

    for (int w = wv; w < nk; w += 4) {
        int rec = klist[seg * KPB + w];
        float ts = kts[seg * KPB + w];
        int j = rec & 1023;
        int i = (rec >> 10) & 255;
        int b = rec >> 18;
        const float* d = dst + b * HWIMG;
        const float* td = thD + b * HWIMG;

        float best = 1e9f;
        int bk = 1 << 20;
#pragma unroll
        for (int rr = 0; rr < 2; ++rr) {
            int k = lane + rr * 64;
            if (k < K) {
                int ii = i + koy[k], jj = j + kox[k];
                if (ii >= 0 && ii < HH && jj >= 0 && jj < WW && d[ii * WW + jj] > 0.5f) {
                    float sc = kd[k] + 10.5f * (1.0f - cosf(ts - td[ii * WW + jj]));
                    if (sc < best || (sc == best && k < bk)) { best = sc; bk = k; }
                }
            }
        }
#pragma unroll
        for (int off = 32; off >= 1; off >>= 1) {
            float ob = __shfl_down(best, off, 64);
            int ok = __shfl_down(bk, off, 64);
            if (ob < best || (ob == best && ok < bk)) { best = ob; bk = ok; }
        }
        if (lane == 0 && best < 5e8f) {
            int dx = kox[bk], dy = koy[bk];
            int packed = j | (i << 10) | ((dx + 7) << 18) | ((dy + 3) << 22);
            int tx0 = max(j - 10, 0) >> 5, tx1 = min(j + 10, WW - 1) >> 5;
            int ty0 = max(i - 10, 0) >> 5, ty1 = min(i + 10, HH - 1) >> 5;
            for (int ty = ty0; ty <= ty1; ++ty)
                for (int tx = tx0; tx <= tx1; ++tx) {
                    int tile = (b * TYN + ty) * TXN + tx;
                    int pos = atomicAdd(&counts[tile], 1);   // 416 addrs, low contention
                    if (pos < CAP) entries[tile * CAP + pos] = packed;
                }
        }
    }
}

// ---------------------------------------------------------------------------
// Pass 3: per-tile sparse diffusion.
// ---------------------------------------------------------------------------
__global__ void diffuse_kernel(const int* __restrict__ counts, const int* __restrict__ entries,
                               float* __restrict__ out) {
    __shared__ float wt[441];
    __shared__ float4 ent[CAP];
    int tid = threadIdx.y * 32 + threadIdx.x;
    for (int t = tid; t < 441; t += 256) {
        int dy = t / 21 - 10;
        int dx = t % 21 - 10;
        wt[t] = expf(-sqrtf((float)(dx * dx + dy * dy)) / 5.0f);
    }
    int tx = blockIdx.x, ty = blockIdx.y, b = blockIdx.z;
    int tile = (b * TYN + ty) * TXN + tx;
    int cnt = counts[tile];
    if (cnt > CAP) cnt = CAP;
    const int* e = entries + tile * CAP;
    for (int t = tid; t < cnt; t += 256) {
        int p = e[t];
        ent[t] = make_float4((float)(p & 1023), (float)((p >> 10) & 255),
                             (float)(((p >> 18) & 15) - 7), (float)(((p >> 22) & 7) - 3));
    }
    __syncthreads();

    int j = tx * 32 + threadIdx.x;
    int i0 = ty * 32 + threadIdx.y * 4;
    float nx0 = 0, ny0 = 0, de0 = 0;
    float nx1 = 0, ny1 = 0, de1 = 0;
    float nx2 = 0, ny2 = 0, de2 = 0;
    float nx3 = 0, ny3 = 0, de3 = 0;

    for (int c = 0; c < cnt; ++c) {
        float4 E = ent[c];
        int dj = (int)E.x - j;
        if (dj < -10 || dj > 10) continue;
        int di = (int)E.y - i0;
        const float* wrow = &wt[dj + 10];
        if (di >= -10 && di <= 10) { float w = wrow[(di + 10) * 21]; de0 += w; nx0 += w * E.z; ny0 += w * E.w; }
        if (di >= -9  && di <= 11) { float w = wrow[(di + 9)  * 21]; de1 += w; nx1 += w * E.z; ny1 += w * E.w; }
        if (di >= -8  && di <= 12) { float w = wrow[(di + 8)  * 21]; de2 += w; nx2 += w * E.z; ny2 += w * E.w; }
        if (di >= -7  && di <= 13) { float w = wrow[(di + 7)  * 21]; de3 += w; nx3 += w * E.z; ny3 += w * E.w; }
    }

    int obase = b * 2 * HWIMG;
    float inv;
    inv = 0.6f / (de0 + 1e-6f);
    out[obase + (i0 + 0) * WW + j] = (float)j + nx0 * inv;
    out[obase + HWIMG + (i0 + 0) * WW + j] = (float)(i0 + 0) + ny0 * inv;
    inv = 0.6f / (de1 + 1e-6f);
    out[obase + (i0 + 1) * WW + j] = (float)j + nx1 * inv;
    out[obase + HWIMG + (i0 + 1) * WW + j] = (float)(i0 + 1) + ny1 * inv;
    inv = 0.6f / (de2 + 1e-6f);
    out[obase + (i0 + 2) * WW + j] = (float)j + nx2 * inv;
    out[obase + HWIMG + (i0 + 2) * WW + j] = (float)(i0 + 2) + ny2 * inv;
    inv = 0.6f / (de3 + 1e-6f);
    out[obase + (i0 + 3) * WW + j] = (float)j + nx3 * inv;
    out[obase + HWIMG + (i0 + 3) * WW + j] = (float)(i0 + 3) + ny3 * inv;
}

// ---------------------------------------------------------------------------
extern "C" void kernel_launch(void* const* d_in, const int* in_sizes, int n_in,
                              void* d_out, int out_size, void* d_ws, size_t ws_size,
                              hipStream_t stream) {
    const float* src = (const float*)d_in[0];
    const float* dst = (const float*)d_in[1];
    const int* xx = (const int*)d_in[2];
    const int* yy = (const int*)d_in[3];
    int K = in_sizes[2];  // 105

    float* ws = (float*)d_ws;
    float* thD   = ws;                              // [BHW]
    int* counts  = (int*)(ws + (size_t)BHW);        // [NTILES]
    int* kcnt    = counts + NTILES;                 // [NTILES]  (grid==NTILES)
    int* klist   = kcnt + NTILES;                   // [NTILES*KPB]
    float* kts   = (float*)(klist + NTILES * KPB);  // [NTILES*KPB]
    int* entries = (int*)(kts + NTILES * KPB);      // [NTILES*CAP]
    float* out = (float*)d_out;

    prep_kernel<<<dim3(BHW / 1024), dim3(256), 0, stream>>>(
        (const float4*)src, (const float4*)dst, src, dst, thD, kcnt, klist, kts, counts);
    search_kernel<<<dim3(NTILES), dim3(256), 0, stream>>>(
        dst, thD, xx, yy, K, kcnt, klist, kts, counts, entries);
    diffuse_kernel<<<dim3(TXN, TYN, BB), dim3(32, 8), 0, stream>>>(counts, entries, out);
}

// Round 7
// 110.714 us; speedup vs baseline: 1.5938x; 1.0926x over previous
//
#include <hip/hip_runtime.h>
#include <math.h>

#define BB 2
#define HH 256
#define WW 832
#define HWIMG (HH * WW)
#define BHW (BB * HWIMG)

#define TXN 26            // tiles in x (832/32)
#define TYN 8             // tiles in y (256/32)
#define NTILES (BB * TXN * TYN)   // 416
#define CAP 512           // per-tile candidate capacity
#define LDSK 128          // per-block keeper capacity (expect ~3, max ~tens)

// ---------------------------------------------------------------------------
// Orientation at (i,j): 3x3 wrap box-blur (jnp.roll) -> jnp.gradient
// (one-sided at borders) -> atan2. Box sums of 0/1 exact in fp32; all 25
// loads independent -> one memory round trip. Bit-identical to dense pass.
// ---------------------------------------------------------------------------
__device__ inline float theta_at(const float* __restrict__ m, int i, int j) {
    int ri[5], cj[5];
#pragma unroll
    for (int t = 0; t < 5; ++t) {
        int r = i + t - 2; r = (r < 0) ? r + HH : (r >= HH ? r - HH : r);
        int c = j + t - 2; c = (c < 0) ? c + WW : (c >= WW ? c - WW : c);
        ri[t] = r * WW; cj[t] = c;
    }
    float S[5][5];
#pragma unroll
    for (int a = 0; a < 5; ++a)
#pragma unroll
        for (int c = 0; c < 5; ++c)
            S[a][c] = m[ri[a] + cj[c]];
    float ct[5], cm[5], cb[5];
#pragma unroll
    for (int c = 0; c < 5; ++c) {
        ct[c] = S[0][c] + S[1][c] + S[2][c];
        cm[c] = S[1][c] + S[2][c] + S[3][c];
        cb[c] = S[2][c] + S[3][c] + S[4][c];
    }
    float Bm = ct[1] + ct[2] + ct[3];
    float Bp = cb[1] + cb[2] + cb[3];
    float Bl = cm[0] + cm[1] + cm[2];
    float Br = cm[2] + cm[3] + cm[4];
    float Bc = cm[1] + cm[2] + cm[3];
    float gy = (i == 0) ? (Bp - Bc) : (i == HH - 1) ? (Bc - Bm) : 0.5f * (Bp - Bm);
    float gx = (j == 0) ? (Br - Bc) : (j == WW - 1) ? (Bc - Bl) : 0.5f * (Br - Bl);
    return atan2f(gy, gx);
}

// ---------------------------------------------------------------------------
// Fused keeper-detect + correspondence search. 1 px/thread, 1664 blocks.
// Phase 1: classify src edges, 5x5 min-lin-index keeper test (12 independent
//          probes), keepers -> LDS list (LDS atomic, on-CU).
// Phase 2: wave-per-keeper 105-offset search; dst-edge orientation is
//          recomputed at hit positions (no thD array, no cross-block dep).
//          Lexicographic (score,k) shuffle argmin == jnp.argmin.
// Output: per-tile candidate bins (counts/entries), 416 spread addresses.
// ---------------------------------------------------------------------------
__global__ void fused_kernel(const float* __restrict__ src, const float* __restrict__ dst,
                             const int* __restrict__ xx, const int* __restrict__ yy, int K,
                             int* __restrict__ counts, int* __restrict__ entries) {
    __shared__ int kox[128], koy[128];
    __shared__ float kd[128];
    __shared__ int recs[LDSK];
    __shared__ float tss[LDSK];
    __shared__ int nkeep;

    int tid = threadIdx.x;
    if (tid == 0) nkeep = 0;
    for (int t = tid; t < K; t += 256) {
        int ox = xx[t], oy = yy[t];
        kox[t] = ox; koy[t] = oy;
        kd[t] = 20.0f * sqrtf((float)(ox * ox + oy * oy));
    }
    __syncthreads();

    // ---- Phase 1: keeper detection (1 coalesced load + sparse slow path) ----
    int idx = blockIdx.x * 256 + tid;          // blocks never straddle batches
    int j = idx % WW;
    int r = idx / WW;
    int i = r % HH;
    int b = r / HH;
    const float* sb = src + b * HWIMG;
    const float* db = dst + b * HWIMG;

    if (sb[i * WW + j] > 0.5f) {
        // smaller-linear-index neighbors: rows i-2,i-1 (dj -2..2), row i (dj -2,-1)
        float m = 0.f;
#pragma unroll
        for (int p = 0; p < 12; ++p) {
            int di = (p < 5) ? -2 : (p < 10 ? -1 : 0);
            int dj = (p < 5) ? (p - 2) : (p < 10 ? (p - 7) : (p - 12));
            int ii = i + di, jj = j + dj;
            bool inb = (ii >= 0) && (jj >= 0) && (jj < WW);
            float v = sb[inb ? (ii * WW + jj) : 0];
            m = fmaxf(m, inb ? v : 0.f);
        }
        if (m <= 0.5f) {
            float ts = theta_at(sb, i, j);
            int pos = atomicAdd(&nkeep, 1);    // LDS atomic
            if (pos < LDSK) {
                recs[pos] = j | (i << 10) | (b << 18);
                tss[pos] = ts;
            }
        }
    }
    __syncthreads();

    // ---- Phase 2: wave-per-keeper search ----
    int nk = (nkeep < LDSK) ? nkeep : LDSK;
    int lane = tid & 63;
    int wv = tid >> 6;                          // 0..3
    for (int w = wv; w < nk; w += 4) {
        int rec = recs[w];
        float ts = tss[w];
        int kj = rec & 1023;
        int ki = (rec >> 10) & 255;
        int kb = rec >> 18;
        const float* d = dst + kb * HWIMG;

        float best = 1e9f;
        int bk = 1 << 20;
#pragma unroll
        for (int rr = 0; rr < 2; ++rr) {
            int k = lane + rr * 64;
            if (k < K) {
                int ii = ki + koy[k], jj = kj + kox[k];
                if (ii >= 0 && ii < HH && jj >= 0 && jj < WW && d[ii * WW + jj] > 0.5f) {
                    float td = theta_at(d, ii, jj);   // ~2 active lanes/wave
                    float sc = kd[k] + 10.5f * (1.0f - cosf(ts - td));
                    if (sc < best || (sc == best && k < bk)) { best = sc; bk = k; }
                }
            }
        }
#pragma unroll
        for (int off = 32; off >= 1; off >>= 1) {
            float ob = __shfl_down(best, off, 64);
            int ok = __shfl_down(bk, off, 64);
            if (ob < best || (ob == best && ok < bk)) { best = ob; bk = ok; }
        }
        if (lane == 0 && best < 5e8f) {
            int dx = kox[bk], dy = koy[bk];
            int packed = kj | (ki << 10) | ((dx + 7) << 18) | ((dy + 3) << 22);
            int tx0 = max(kj - 10, 0) >> 5, tx1 = min(kj + 10, WW - 1) >> 5;
            int ty0 = max(ki - 10, 0) >> 5, ty1 = min(ki + 10, HH - 1) >> 5;
            for (int ty = ty0; ty <= ty1; ++ty)
                for (int tx = tx0; tx <= tx1; ++tx) {
                    int tile = (kb * TYN + ty) * TXN + tx;
                    int pos = atomicAdd(&counts[tile], 1);   // 416 addrs, ~23 each
                    if (pos < CAP) entries[tile * CAP + pos] = packed;
                }
        }
    }
}

// ---------------------------------------------------------------------------
// Per-tile sparse diffusion: one block per 32x32 tile, candidates in LDS,
// each thread accumulates 4 pixels over the broadcast candidate list.
// ---------------------------------------------------------------------------
__global__ void diffuse_kernel(const int* __restrict__ counts, const int* __restrict__ entries,
                               float* __restrict__ out) {
    __shared__ float wt[441];
    __shared__ float4 ent[CAP];
    int tid = threadIdx.y * 32 + threadIdx.x;
    for (int t = tid; t < 441; t += 256) {
        int dy = t / 21 - 10;
        int dx = t % 21 - 10;
        wt[t] = expf(-sqrtf((float)(dx * dx + dy * dy)) / 5.0f);
    }
    int tx = blockIdx.x, ty = blockIdx.y, b = blockIdx.z;
    int tile = (b * TYN + ty) * TXN + tx;
    int cnt = counts[tile];
    if (cnt > CAP) cnt = CAP;
    const int* e = entries + tile * CAP;
    for (int t = tid; t < cnt; t += 256) {
        int p = e[t];
        ent[t] = make_float4((float)(p & 1023), (float)((p >> 10) & 255),
                             (float)(((p >> 18) & 15) - 7), (float)(((p >> 22) & 7) - 3));
    }
    __syncthreads();

    int j = tx * 32 + threadIdx.x;
    int i0 = ty * 32 + threadIdx.y * 4;
    float nx0 = 0, ny0 = 0, de0 = 0;
    float nx1 = 0, ny1 = 0, de1 = 0;
    float nx2 = 0, ny2 = 0, de2 = 0;
    float nx3 = 0, ny3 = 0, de3 = 0;

    for (int c = 0; c < cnt; ++c) {
        float4 E = ent[c];
        int dj = (int)E.x - j;
        if (dj < -10 || dj > 10) continue;
        int di = (int)E.y - i0;
        const float* wrow = &wt[dj + 10];
        if (di >= -10 && di <= 10) { float w = wrow[(di + 10) * 21]; de0 += w; nx0 += w * E.z; ny0 += w * E.w; }
        if (di >= -9  && di <= 11) { float w = wrow[(di + 9)  * 21]; de1 += w; nx1 += w * E.z; ny1 += w * E.w; }
        if (di >= -8  && di <= 12) { float w = wrow[(di + 8)  * 21]; de2 += w; nx2 += w * E.z; ny2 += w * E.w; }
        if (di >= -7  && di <= 13) { float w = wrow[(di + 7)  * 21]; de3 += w; nx3 += w * E.z; ny3 += w * E.w; }
    }

    int obase = b * 2 * HWIMG;
    float inv;
    inv = 0.6f / (de0 + 1e-6f);
    out[obase + (i0 + 0) * WW + j] = (float)j + nx0 * inv;
    out[obase + HWIMG + (i0 + 0) * WW + j] = (float)(i0 + 0) + ny0 * inv;
    inv = 0.6f / (de1 + 1e-6f);
    out[obase + (i0 + 1) * WW + j] = (float)j + nx1 * inv;
    out[obase + HWIMG + (i0 + 1) * WW + j] = (float)(i0 + 1) + ny1 * inv;
    inv = 0.6f / (de2 + 1e-6f);
    out[obase + (i0 + 2) * WW + j] = (float)j + nx2 * inv;
    out[obase + HWIMG + (i0 + 2) * WW + j] = (float)(i0 + 2) + ny2 * inv;
    inv = 0.6f / (de3 + 1e-6f);
    out[obase + (i0 + 3) * WW + j] = (float)j + nx3 * inv;
    out[obase + HWIMG + (i0 + 3) * WW + j] = (float)(i0 + 3) + ny3 * inv;
}

// ---------------------------------------------------------------------------
extern "C" void kernel_launch(void* const* d_in, const int* in_sizes, int n_in,
                              void* d_out, int out_size, void* d_ws, size_t ws_size,
                              hipStream_t stream) {
    const float* src = (const float*)d_in[0];
    const float* dst = (const float*)d_in[1];
    const int* xx = (const int*)d_in[2];
    const int* yy = (const int*)d_in[3];
    int K = in_sizes[2];  // 105

    int* counts  = (int*)d_ws;                 // [NTILES]
    int* entries = counts + NTILES;            // [NTILES*CAP]
    float* out = (float*)d_out;

    hipMemsetAsync(counts, 0, NTILES * sizeof(int), stream);
    fused_kernel<<<dim3(BHW / 256), dim3(256), 0, stream>>>(
        src, dst, xx, yy, K, counts, entries);
    diffuse_kernel<<<dim3(TXN, TYN, BB), dim3(32, 8), 0, stream>>>(counts, entries, out);
}